// Round 6
// baseline (209.945 us; speedup 1.0000x reference)
//
#include <hip/hip_runtime.h>
#include <hip/hip_bf16.h>
#include <math.h>

#define NN   10000
#define HIDD 512
#define BP   4096
#define KPAD 10048      // 157 * 64
#define KITER1 157
#define KSPLIT 4

typedef short bf16x8 __attribute__((ext_vector_type(8)));
typedef float f32x4  __attribute__((ext_vector_type(4)));
typedef unsigned short u16x4 __attribute__((ext_vector_type(4)));
typedef unsigned short u16x8 __attribute__((ext_vector_type(8)));

__device__ __forceinline__ unsigned short f2bf(float f) {
  union { float f; unsigned u; } v; v.f = f;
  unsigned r = v.u + 0x7FFFu + ((v.u >> 16) & 1u);   // RN-even
  return (unsigned short)(r >> 16);
}
__device__ __forceinline__ float bf2f(unsigned short u) {
  union { unsigned u; float f; } v; v.u = ((unsigned)u) << 16;
  return v.f;
}
__device__ __forceinline__ void gload_lds16(const void* g, void* l) {
  __builtin_amdgcn_global_load_lds((const __attribute__((address_space(1))) unsigned int*)g,
                                   (__attribute__((address_space(3))) unsigned int*)l, 16, 0, 0);
}

// src f32 [K][512] -> dst bf16 [512][Kpadw], zero-padded for k in [K, Kpadw)
__global__ void transpose_cvt(const float* __restrict__ src, unsigned short* __restrict__ dst,
                              int K, int Kpadw) {
  __shared__ float tile[32][33];
  int k0 = blockIdx.x * 32, n0 = blockIdx.y * 32;
  int t = threadIdx.x, c = t & 31, r = t >> 5;
  #pragma unroll
  for (int i = 0; i < 4; ++i) {
    int k = k0 + r + i * 8;
    float v = (k < K) ? src[(size_t)k * 512 + (n0 + c)] : 0.f;
    tile[r + i * 8][c] = v;
  }
  __syncthreads();
  #pragma unroll
  for (int i = 0; i < 4; ++i) {
    int n = n0 + r + i * 8;
    dst[(size_t)n * Kpadw + (k0 + c)] = f2bf(tile[c][r + i * 8]);
  }
}

// 4 x (512x512 transpose+cvt) in one launch; blockIdx.z selects the weight.
__global__ void transpose_cvt4(const float* __restrict__ s0, const float* __restrict__ s1,
                               const float* __restrict__ s2, const float* __restrict__ s3,
                               unsigned short* __restrict__ d0, unsigned short* __restrict__ d1,
                               unsigned short* __restrict__ d2, unsigned short* __restrict__ d3) {
  __shared__ float tile[32][33];
  const float* src = (blockIdx.z == 0) ? s0 : (blockIdx.z == 1) ? s1 : (blockIdx.z == 2) ? s2 : s3;
  unsigned short* dst = (blockIdx.z == 0) ? d0 : (blockIdx.z == 1) ? d1 : (blockIdx.z == 2) ? d2 : d3;
  int k0 = blockIdx.x * 32, n0 = blockIdx.y * 32;
  int t = threadIdx.x, c = t & 31, r = t >> 5;
  #pragma unroll
  for (int i = 0; i < 4; ++i)
    tile[r + i * 8][c] = src[(size_t)(k0 + r + i * 8) * 512 + (n0 + c)];
  __syncthreads();
  #pragma unroll
  for (int i = 0; i < 4; ++i)
    dst[(size_t)(n0 + r + i * 8) * 512 + (k0 + c)] = f2bf(tile[c][r + i * 8]);
}

// Gather-GEMM: Ppart[ksp][8192][512] = A[gather rows] @ W1T^T over K-chunk ksp.
// Block 128m x 512n x BK=64; 512 threads = 8 waves (2m x 4n), wave-tile 64x128.
// As: 16 KB single-buffer (reg-staged f32->bf16). Bs: 2 x 64 KB double-buffer via
// global_load_lds, swizzle folded into the global source address.
// Pipeline (2 barriers, compiler-scheduled waits):
//   WRITEA(t) -> barrier1 -> issue B(t+1)/A(t+1) -> compute(t) -> barrier2
// B(t+1) and A(t+1) get the full MFMA phase of cover before barrier2's vmcnt(0)
// drain; barrier1 drains nothing outstanding. A rows read exactly once (BN=512).
__global__ __launch_bounds__(512, 2)
void gather_gemm(const float* __restrict__ A, const unsigned short* __restrict__ BT,
                 float* __restrict__ Ppart,
                 const int* __restrict__ idxx, const int* __restrict__ idxy) {
  __shared__ __align__(16) char As[128 * 128];      // 128 rows x 64 bf16, XOR-swizzled granules
  __shared__ __align__(16) char Bs[2][512 * 128];   // dbuf: 512 n-rows x 64 bf16 each
  const int tid  = threadIdx.x;
  const int lane = tid & 63;
  const int wave = tid >> 6;            // 0..7
  const int wm   = wave >> 2;           // 0..1 -> m offset wm*64
  const int wn   = wave & 3;            // 0..3 -> n offset wn*128
  const int m0   = blockIdx.y * 128;
  const int ksp  = blockIdx.x;          // 0..3 ; XCD j serves ksp = j%4 (L2-resident B slice)
  const int t0   = (ksp * KITER1) / KSPLIT;
  const int t1   = ((ksp + 1) * KITER1) / KSPLIT;

  // A staging: 4 threads/row, thread covers 16 consecutive floats (4 float4)
  const int sr = tid >> 2, sp = tid & 3;
  int m = m0 + sr;
  int g = (m < BP) ? idxx[m] : idxy[m - BP];
  const float* arow = A + (size_t)g * NN;

  // B staging: 8 gload_lds chunks of 1 KB per wave; wave covers rows [wave*64,+64).
  // lane covers row wave*64 + j*8 + (lane>>3); LDS slot lane&7 <- global granule
  // (lane&7)^(row&7) = (lane&7)^(lane>>3).
  const unsigned short* bsrc0 =
      BT + (size_t)((wave << 6) + (lane >> 3)) * KPAD + (((lane & 7) ^ (lane >> 3)) << 3);

  f32x4 acc[4][8];
  #pragma unroll
  for (int i = 0; i < 4; ++i)
    #pragma unroll
    for (int j = 0; j < 8; ++j) acc[i][j] = (f32x4){0.f, 0.f, 0.f, 0.f};

  float4 ar[4];

  auto LOADA = [&](int t) {
    int kb = t * 64 + sp * 16;
    #pragma unroll
    for (int j = 0; j < 4; ++j) {
      int ka = kb + j * 4;
      if (ka < NN) ar[j] = *(const float4*)(arow + ka);
      else         ar[j] = make_float4(0.f, 0.f, 0.f, 0.f);
    }
  };
  auto ISSUEB = [&](int t, int buf) {
    const unsigned short* s = bsrc0 + (size_t)t * 64;
    char* d = Bs[buf] + (wave << 13);
    #pragma unroll
    for (int j = 0; j < 8; ++j)
      gload_lds16(s + (size_t)j * 8 * KPAD, d + j * 1024);
  };
  auto WRITEA = [&]() {
    #pragma unroll
    for (int q = 0; q < 2; ++q) {
      u16x8 o;
      o[0] = f2bf(ar[2*q].x);   o[1] = f2bf(ar[2*q].y);
      o[2] = f2bf(ar[2*q].z);   o[3] = f2bf(ar[2*q].w);
      o[4] = f2bf(ar[2*q+1].x); o[5] = f2bf(ar[2*q+1].y);
      o[6] = f2bf(ar[2*q+1].z); o[7] = f2bf(ar[2*q+1].w);
      int gq = sp * 2 + q;
      *(u16x8*)(As + sr * 128 + ((gq ^ (sr & 7)) << 4)) = o;
    }
  };

  LOADA(t0);
  ISSUEB(t0, 0);
  int cur = 0;
  for (int t = t0; t < t1; ++t) {
    WRITEA();                          // compiler waits A(t) regs (covered by prev compute)
    __syncthreads();                   // barrier1: As(t) visible; Bs[cur](t) ready
    if (t + 1 < t1) {                  // issue right AFTER barrier -> full compute of cover
      ISSUEB(t + 1, cur ^ 1);
      LOADA(t + 1);
    }
    const char* Bc = Bs[cur];
    #pragma unroll
    for (int ks = 0; ks < 2; ++ks) {
      int kg = ks * 4 + (lane >> 4);
      bf16x8 af[4]; bf16x8 bfr[8];
      #pragma unroll
      for (int i = 0; i < 4; ++i) {
        int r = wm * 64 + i * 16 + (lane & 15);
        af[i] = *(const bf16x8*)(As + r * 128 + ((kg ^ (r & 7)) << 4));
      }
      #pragma unroll
      for (int j = 0; j < 8; ++j) {
        int n = wn * 128 + j * 16 + (lane & 15);
        bfr[j] = *(const bf16x8*)(Bc + n * 128 + ((kg ^ (n & 7)) << 4));
      }
      #pragma unroll
      for (int i = 0; i < 4; ++i)
        #pragma unroll
        for (int j = 0; j < 8; ++j)
          acc[i][j] = __builtin_amdgcn_mfma_f32_16x16x32_bf16(af[i], bfr[j], acc[i][j], 0, 0, 0);
    }
    __syncthreads();                   // barrier2: LDS readers done; drains B(t+1)/A(t+1)
    cur ^= 1;
  }

  float* Cb = Ppart + (size_t)ksp * (8192 * 512);
  #pragma unroll
  for (int i = 0; i < 4; ++i) {
    #pragma unroll
    for (int j = 0; j < 8; ++j) {
      int row = m0 + wm * 64 + i * 16 + ((lane >> 4) << 2);
      int col = wn * 128 + j * 16 + (lane & 15);
      #pragma unroll
      for (int rr = 0; rr < 4; ++rr)
        Cb[(size_t)(row + rr) * 512 + col] = acc[i][j][rr];
    }
  }
}

// Fused highway layer: h = x@Wh + bh, g = x@Wg + bg in one tile pass;
// epilogue: xout = relu(h)*sigmoid(g) + x*(1-sigmoid(g)), bf16.
__global__ __launch_bounds__(256)
void hwy_gemm(const unsigned short* __restrict__ xin, const unsigned short* __restrict__ WcT,
              const float* __restrict__ bh, const float* __restrict__ bg,
              unsigned short* __restrict__ xout) {
  __shared__ __align__(16) char As[128 * 128];
  __shared__ __align__(16) char Bs[128 * 128];   // rows 0-63: Wh^T n0+..; 64-127: Wg^T 512+n0+..
  const int tid  = threadIdx.x;
  const int lane = tid & 63;
  const int wave = tid >> 6;
  const int wm = wave >> 1, wn = wave & 1;
  const int m0 = blockIdx.y * 128;
  const int n0 = blockIdx.x * 64;

  const int sr = tid >> 1, sp = tid & 1;
  const unsigned short* arow16 = xin + (size_t)(m0 + sr) * HIDD;
  const int rb = tid >> 1;
  const int grow = (rb < 64) ? (n0 + rb) : (512 + n0 + rb - 64);
  const unsigned short* brow = WcT + (size_t)grow * HIDD;

  f32x4 acc[4][2][2];
  #pragma unroll
  for (int i = 0; i < 4; ++i)
    #pragma unroll
    for (int j = 0; j < 2; ++j)
      #pragma unroll
      for (int p = 0; p < 2; ++p) acc[i][j][p] = (f32x4){0.f, 0.f, 0.f, 0.f};

  u16x8 ar16[4], br16[4];

  auto LOADREGS = [&](int t) {
    int k0 = t * 64;
    #pragma unroll
    for (int j = 0; j < 4; ++j)
      ar16[j] = *(const u16x8*)(arow16 + k0 + (sp * 4 + j) * 8);
    #pragma unroll
    for (int q = 0; q < 4; ++q)
      br16[q] = *(const u16x8*)(brow + k0 + (sp * 4 + q) * 8);
  };
  auto WRITELDS = [&]() {
    #pragma unroll
    for (int j = 0; j < 4; ++j) {
      int gq = sp * 4 + j;
      *(u16x8*)(As + sr * 128 + ((gq ^ (sr & 7)) << 4)) = ar16[j];
    }
    #pragma unroll
    for (int q = 0; q < 4; ++q) {
      int gq = sp * 4 + q;
      *(u16x8*)(Bs + rb * 128 + ((gq ^ (rb & 7)) << 4)) = br16[q];
    }
  };

  for (int t = 0; t < 8; ++t) {
    if (t == 0) LOADREGS(0);
    else __syncthreads();
    WRITELDS();
    if (t + 1 < 8) LOADREGS(t + 1);
    __syncthreads();
    #pragma unroll
    for (int ks = 0; ks < 2; ++ks) {
      bf16x8 af[4]; bf16x8 bfr[2][2];
      int kg = ks * 4 + (lane >> 4);
      #pragma unroll
      for (int i = 0; i < 4; ++i) {
        int r = wm * 64 + i * 16 + (lane & 15);
        af[i] = *(const bf16x8*)(As + r * 128 + ((kg ^ (r & 7)) << 4));
      }
      #pragma unroll
      for (int j = 0; j < 2; ++j)
        #pragma unroll
        for (int p = 0; p < 2; ++p) {
          int n = p * 64 + wn * 32 + j * 16 + (lane & 15);
          bfr[j][p] = *(const bf16x8*)(Bs + n * 128 + ((kg ^ (n & 7)) << 4));
        }
      #pragma unroll
      for (int i = 0; i < 4; ++i)
        #pragma unroll
        for (int j = 0; j < 2; ++j)
          #pragma unroll
          for (int p = 0; p < 2; ++p)
            acc[i][j][p] = __builtin_amdgcn_mfma_f32_16x16x32_bf16(af[i], bfr[j][p], acc[i][j][p], 0, 0, 0);
    }
  }

  #pragma unroll
  for (int j = 0; j < 2; ++j) {
    int col = n0 + wn * 32 + j * 16 + (lane & 15);
    float bhv = bh[col], bgv = bg[col];
    #pragma unroll
    for (int i = 0; i < 4; ++i) {
      int row = m0 + wm * 64 + i * 16 + ((lane >> 4) << 2);
      #pragma unroll
      for (int rr = 0; rr < 4; ++rr) {
        float hv = fmaxf(acc[i][j][0][rr] + bhv, 0.f);
        float gv = acc[i][j][1][rr] + bgv;
        float tv = 1.f / (1.f + expf(-gv));
        float xi = bf2f(xin[(size_t)(row + rr) * HIDD + col]);
        xout[(size_t)(row + rr) * HIDD + col] = f2bf(hv * tv + xi * (1.f - tv));
      }
    }
  }
}

// ex = relu(sum of KSPLIT partials), rows [0,4096)=ex, [4096,8192)=ey
__global__ void pair_combine(const float* __restrict__ P, unsigned short* __restrict__ xb) {
  int i = blockIdx.x * 256 + threadIdx.x;       // 4096*512/4 float4 groups
  const size_t qs = (size_t)8192 * 512 / 4;
  const size_t yoff = (size_t)BP * HIDD / 4;
  float4 a = ((const float4*)P)[i];
  float4 b = ((const float4*)P)[i + yoff];
  #pragma unroll
  for (int q = 1; q < KSPLIT; ++q) {
    float4 aq = ((const float4*)P)[i + q * qs];
    float4 bq = ((const float4*)P)[i + yoff + q * qs];
    a.x += aq.x; a.y += aq.y; a.z += aq.z; a.w += aq.w;
    b.x += bq.x; b.y += bq.y; b.z += bq.z; b.w += bq.w;
  }
  const float s = 0.04419417382415922f;    // 1/sqrt(512)
  float ex, ey, d;
  u16x4 o;
  ex = fmaxf(a.x, 0.f); ey = fmaxf(b.x, 0.f); d = ex - ey; o[0] = f2bf(d * d * s);
  ex = fmaxf(a.y, 0.f); ey = fmaxf(b.y, 0.f); d = ex - ey; o[1] = f2bf(d * d * s);
  ex = fmaxf(a.z, 0.f); ey = fmaxf(b.z, 0.f); d = ex - ey; o[2] = f2bf(d * d * s);
  ex = fmaxf(a.w, 0.f); ey = fmaxf(b.w, 0.f); d = ex - ey; o[3] = f2bf(d * d * s);
  ((u16x4*)xb)[i] = o;
}

// logits + 2-class log_softmax, one wave per row
__global__ void logits_lsm(const unsigned short* __restrict__ x2, const float* __restrict__ Wl,
                           const float* __restrict__ bl, float* __restrict__ out) {
  int gw = (blockIdx.x * blockDim.x + threadIdx.x) >> 6;
  int lane = threadIdx.x & 63;
  const unsigned short* xr = x2 + (size_t)gw * HIDD;
  u16x8 xv = *(const u16x8*)(xr + lane * 8);
  float4 w0 = ((const float4*)Wl)[lane * 4 + 0];
  float4 w1 = ((const float4*)Wl)[lane * 4 + 1];
  float4 w2 = ((const float4*)Wl)[lane * 4 + 2];
  float4 w3 = ((const float4*)Wl)[lane * 4 + 3];
  float xs[8];
  #pragma unroll
  for (int j = 0; j < 8; ++j) xs[j] = bf2f(xv[j]);
  float s0 = xs[0]*w0.x + xs[1]*w0.z + xs[2]*w1.x + xs[3]*w1.z
           + xs[4]*w2.x + xs[5]*w2.z + xs[6]*w3.x + xs[7]*w3.z;
  float s1 = xs[0]*w0.y + xs[1]*w0.w + xs[2]*w1.y + xs[3]*w1.w
           + xs[4]*w2.y + xs[5]*w2.w + xs[6]*w3.y + xs[7]*w3.w;
  #pragma unroll
  for (int off = 32; off; off >>= 1) { s0 += __shfl_down(s0, off); s1 += __shfl_down(s1, off); }
  if (lane == 0) {
    float l0 = s0 + bl[0], l1 = s1 + bl[1];
    float mx = fmaxf(l0, l1);
    float lse = mx + logf(expf(l0 - mx) + expf(l1 - mx));
    out[(size_t)gw * 2 + 0] = l0 - lse;
    out[(size_t)gw * 2 + 1] = l1 - lse;
  }
}

extern "C" void kernel_launch(void* const* d_in, const int* in_sizes, int n_in,
                              void* d_out, int out_size, void* d_ws, size_t ws_size,
                              hipStream_t stream) {
  const float* A   = (const float*)d_in[0];
  const float* W1  = (const float*)d_in[1];
  const float* Wh0 = (const float*)d_in[2];
  const float* bh0 = (const float*)d_in[3];
  const float* Wg0 = (const float*)d_in[4];
  const float* bg0 = (const float*)d_in[5];
  const float* Wh1 = (const float*)d_in[6];
  const float* bh1 = (const float*)d_in[7];
  const float* Wg1 = (const float*)d_in[8];
  const float* bg1 = (const float*)d_in[9];
  const float* Wl  = (const float*)d_in[10];
  const float* bl  = (const float*)d_in[11];
  const int* idxx  = (const int*)d_in[12];
  const int* idxy  = (const int*)d_in[13];
  float* out = (float*)d_out;

  char* w = (char*)d_ws;
  auto carve = [&](size_t bytes) { char* p = w; w += (bytes + 255) & ~(size_t)255; return p; };
  unsigned short* W1T  = (unsigned short*)carve((size_t)512 * KPAD * 2);
  unsigned short* WcT0 = (unsigned short*)carve((size_t)1024 * 512 * 2);
  unsigned short* WcT1 = (unsigned short*)carve((size_t)1024 * 512 * 2);
  float* Ppart         = (float*)carve((size_t)KSPLIT * 8192 * 512 * 4);
  unsigned short* xb0  = (unsigned short*)carve((size_t)4096 * 512 * 2);
  unsigned short* xb1  = (unsigned short*)carve((size_t)4096 * 512 * 2);
  unsigned short* xb2  = (unsigned short*)carve((size_t)4096 * 512 * 2);

  // weight prep (~31 MB traffic, 2 launches)
  transpose_cvt<<<dim3(KPAD / 32, 16), 256, 0, stream>>>(W1, W1T, NN, KPAD);
  transpose_cvt4<<<dim3(16, 16, 4), 256, 0, stream>>>(
      Wh0, Wg0, Wh1, Wg1,
      WcT0, WcT0 + (size_t)512 * 512, WcT1, WcT1 + (size_t)512 * 512);

  // Ppart[ksp] = A[gathered rows] @ W1 K-chunk; 256 blocks = 1/CU, dbuf-B pipeline
  gather_gemm<<<dim3(KSPLIT, 64), 512, 0, stream>>>(A, W1T, Ppart, idxx, idxy);
  pair_combine<<<dim3(2048), 256, 0, stream>>>(Ppart, xb0);

  // fused highway layers
  hwy_gemm<<<dim3(8, 32), 256, 0, stream>>>(xb0, WcT0, bh0, bg0, xb1);
  hwy_gemm<<<dim3(8, 32), 256, 0, stream>>>(xb1, WcT1, bh1, bg1, xb2);

  logits_lsm<<<dim3(1024), 256, 0, stream>>>(xb2, Wl, bl, out);
}

// Round 8
// 196.314 us; speedup vs baseline: 1.0694x; 1.0694x over previous
//
#include <hip/hip_runtime.h>
#include <hip/hip_bf16.h>
#include <math.h>

#define NN   10000
#define HIDD 512
#define BP   4096
#define KPAD 10048      // 157 * 64
#define KITER1 157
#define KSPLIT 5

typedef short bf16x8 __attribute__((ext_vector_type(8)));
typedef float f32x4  __attribute__((ext_vector_type(4)));
typedef unsigned short u16x4 __attribute__((ext_vector_type(4)));
typedef unsigned short u16x8 __attribute__((ext_vector_type(8)));

__device__ __forceinline__ unsigned short f2bf(float f) {
  union { float f; unsigned u; } v; v.f = f;
  unsigned r = v.u + 0x7FFFu + ((v.u >> 16) & 1u);   // RN-even
  return (unsigned short)(r >> 16);
}
__device__ __forceinline__ float bf2f(unsigned short u) {
  union { unsigned u; float f; } v; v.u = ((unsigned)u) << 16;
  return v.f;
}
__device__ __forceinline__ void gload_lds16(const void* g, void* l) {
  __builtin_amdgcn_global_load_lds((const __attribute__((address_space(1))) unsigned int*)g,
                                   (__attribute__((address_space(3))) unsigned int*)l, 16, 0, 0);
}

// ---- dedup: zero -> flags -> exclusive scan -> compact row list ----
__global__ void zero_flags(int* __restrict__ flags) {
  int i = blockIdx.x * 256 + threadIdx.x;
  if (i < KPAD) flags[i] = 0;
}

// B = 4096 entries in EACH of idxx, idxy
__global__ void mark_rows(const int* __restrict__ idxx, const int* __restrict__ idxy,
                          int* __restrict__ flags) {
  int i = blockIdx.x * 256 + threadIdx.x;   // 0..4095
  flags[idxx[i]] = 1;
  flags[idxy[i]] = 1;
}

// single block, 1024 threads; 10 elements/thread covers 10240 >= NN
__global__ __launch_bounds__(1024)
void scan_compact(const int* __restrict__ flags, int* __restrict__ newpos,
                  int* __restrict__ rows, int* __restrict__ nuniq) {
  __shared__ int part[1024];
  int t = threadIdx.x;
  int base = t * 10;
  int loc[10]; int s = 0;
  #pragma unroll
  for (int j = 0; j < 10; ++j) {
    int idx = base + j;
    int f = (idx < NN) ? flags[idx] : 0;
    loc[j] = s; s += f;
  }
  part[t] = s;
  __syncthreads();
  for (int off = 1; off < 1024; off <<= 1) {
    int v = (t >= off) ? part[t - off] : 0;
    __syncthreads();
    part[t] += v;
    __syncthreads();
  }
  int pre = (t == 0) ? 0 : part[t - 1];   // exclusive prefix
  #pragma unroll
  for (int j = 0; j < 10; ++j) {
    int idx = base + j;
    if (idx < NN) {
      int pos = pre + loc[j];
      newpos[idx] = pos;
      if (flags[idx]) rows[pos] = idx;
    }
  }
  if (t == 1023) nuniq[0] = part[1023];
}

// src f32 [K][512] -> dst bf16 [512][Kpadw], zero-padded for k in [K, Kpadw)
__global__ void transpose_cvt(const float* __restrict__ src, unsigned short* __restrict__ dst,
                              int K, int Kpadw) {
  __shared__ float tile[32][33];
  int k0 = blockIdx.x * 32, n0 = blockIdx.y * 32;
  int t = threadIdx.x, c = t & 31, r = t >> 5;
  #pragma unroll
  for (int i = 0; i < 4; ++i) {
    int k = k0 + r + i * 8;
    float v = (k < K) ? src[(size_t)k * 512 + (n0 + c)] : 0.f;
    tile[r + i * 8][c] = v;
  }
  __syncthreads();
  #pragma unroll
  for (int i = 0; i < 4; ++i) {
    int n = n0 + r + i * 8;
    dst[(size_t)n * Kpadw + (k0 + c)] = f2bf(tile[c][r + i * 8]);
  }
}

// 4 x (512x512 transpose+cvt) in one launch; blockIdx.z selects the weight.
__global__ void transpose_cvt4(const float* __restrict__ s0, const float* __restrict__ s1,
                               const float* __restrict__ s2, const float* __restrict__ s3,
                               unsigned short* __restrict__ d0, unsigned short* __restrict__ d1,
                               unsigned short* __restrict__ d2, unsigned short* __restrict__ d3) {
  __shared__ float tile[32][33];
  const float* src = (blockIdx.z == 0) ? s0 : (blockIdx.z == 1) ? s1 : (blockIdx.z == 2) ? s2 : s3;
  unsigned short* dst = (blockIdx.z == 0) ? d0 : (blockIdx.z == 1) ? d1 : (blockIdx.z == 2) ? d2 : d3;
  int k0 = blockIdx.x * 32, n0 = blockIdx.y * 32;
  int t = threadIdx.x, c = t & 31, r = t >> 5;
  #pragma unroll
  for (int i = 0; i < 4; ++i)
    tile[r + i * 8][c] = src[(size_t)(k0 + r + i * 8) * 512 + (n0 + c)];
  __syncthreads();
  #pragma unroll
  for (int i = 0; i < 4; ++i)
    dst[(size_t)(n0 + r + i * 8) * 512 + (k0 + c)] = f2bf(tile[c][r + i * 8]);
}

// Gather-GEMM over the UNIQUE row list (round-3 structure):
// Ppart[ksp][row][512] = A[rows[row]] @ W1T^T over K-chunk ksp.
// Tile 64m x 512n x BK=64, 512 threads = 8 waves, wave-tile 64x64; 72 KB LDS,
// 2 blocks/CU. Blocks with m0 >= nuniq exit immediately (fixed worst-case grid).
__global__ __launch_bounds__(512, 4)
void gather_gemm(const float* __restrict__ A, const unsigned short* __restrict__ BT,
                 float* __restrict__ Ppart,
                 const int* __restrict__ rows, const int* __restrict__ nuniq_p) {
  __shared__ __align__(16) char As[64 * 128];    // 64 rows x 64 bf16, XOR-swizzled granules
  __shared__ __align__(16) char Bs[512 * 128];   // 512 n-rows x 64 bf16, swizzle via src addr
  const int nuniq = nuniq_p[0];
  const int m0 = blockIdx.y * 64;
  if (m0 >= nuniq) return;
  const int tid  = threadIdx.x;
  const int lane = tid & 63;
  const int wave = tid >> 6;            // 0..7, owns n-range [wave*64, +64)
  const int ksp  = blockIdx.x;          // 0..KSPLIT-1
  const int t0   = (ksp * KITER1) / KSPLIT;
  const int t1   = ((ksp + 1) * KITER1) / KSPLIT;

  // A staging: 8 threads per row, each 8 consecutive floats
  const int sr = tid >> 3, sp = tid & 7;
  int m = m0 + sr;
  int g = rows[(m < nuniq) ? m : (nuniq - 1)];
  const float* arow = A + (size_t)g * NN;

  // B staging: per wave 8 gload_lds chunks of 1 KB (8 rows); lane covers
  // row wave*64 + j*8 + (lane>>3), LDS slot lane&7 <- global granule (lane&7)^(lane>>3)
  const unsigned short* bsrc0 =
      BT + (size_t)(wave * 64 + (lane >> 3)) * KPAD + (((lane & 7) ^ (lane >> 3)) << 3);
  char* bdst0 = Bs + (wave << 13);

  f32x4 acc[4][4];
  #pragma unroll
  for (int i = 0; i < 4; ++i)
    #pragma unroll
    for (int j = 0; j < 4; ++j) acc[i][j] = (f32x4){0.f, 0.f, 0.f, 0.f};

  float4 ar[2];

  auto LOADA = [&](int t) {
    int ka = t * 64 + sp * 8;
    if (ka < NN) {
      ar[0] = *(const float4*)(arow + ka);
      ar[1] = *(const float4*)(arow + ka + 4);
    } else {
      ar[0] = make_float4(0.f, 0.f, 0.f, 0.f);
      ar[1] = make_float4(0.f, 0.f, 0.f, 0.f);
    }
  };
  auto ISSUEB = [&](int t) {
    const unsigned short* s = bsrc0 + (size_t)t * 64;
    #pragma unroll
    for (int j = 0; j < 8; ++j)
      gload_lds16(s + (size_t)j * 8 * KPAD, bdst0 + j * 1024);
  };
  auto WRITEA = [&]() {
    u16x8 o;
    o[0] = f2bf(ar[0].x); o[1] = f2bf(ar[0].y); o[2] = f2bf(ar[0].z); o[3] = f2bf(ar[0].w);
    o[4] = f2bf(ar[1].x); o[5] = f2bf(ar[1].y); o[6] = f2bf(ar[1].z); o[7] = f2bf(ar[1].w);
    *(u16x8*)(As + sr * 128 + ((sp ^ (sr & 7)) << 4)) = o;
  };

  LOADA(t0);
  ISSUEB(t0);
  for (int t = t0; t < t1; ++t) {
    if (t > t0) __syncthreads();      // drains B(t) gloads; As writable again
    WRITEA();                         // compiler waits A(t) regs
    __syncthreads();                  // As(t), Bs(t) visible to all
    if (t + 1 < t1) LOADA(t + 1);     // A prefetch rides under compute
    #pragma unroll
    for (int ks = 0; ks < 2; ++ks) {
      int kg = ks * 4 + (lane >> 4);
      bf16x8 af[4]; bf16x8 bfr[4];
      #pragma unroll
      for (int i = 0; i < 4; ++i) {
        int r = i * 16 + (lane & 15);
        af[i] = *(const bf16x8*)(As + r * 128 + ((kg ^ (r & 7)) << 4));
      }
      #pragma unroll
      for (int j = 0; j < 4; ++j) {
        int n = wave * 64 + j * 16 + (lane & 15);
        bfr[j] = *(const bf16x8*)(Bs + n * 128 + ((kg ^ (n & 7)) << 4));
      }
      #pragma unroll
      for (int i = 0; i < 4; ++i)
        #pragma unroll
        for (int j = 0; j < 4; ++j)
          acc[i][j] = __builtin_amdgcn_mfma_f32_16x16x32_bf16(af[i], bfr[j], acc[i][j], 0, 0, 0);
    }
    __syncthreads();                  // all waves done reading LDS(t)
    if (t + 1 < t1) ISSUEB(t + 1);    // refill Bs for next iter
  }

  float* Cb = Ppart + (size_t)ksp * (8192 * 512);
  #pragma unroll
  for (int i = 0; i < 4; ++i) {
    #pragma unroll
    for (int j = 0; j < 4; ++j) {
      int row = m0 + i * 16 + ((lane >> 4) << 2);
      int col = wave * 64 + j * 16 + (lane & 15);
      #pragma unroll
      for (int rr = 0; rr < 4; ++rr)
        Cb[(size_t)(row + rr) * 512 + col] = acc[i][j][rr];
    }
  }
}

// Fused highway layer: h = x@Wh + bh, g = x@Wg + bg in one tile pass;
// epilogue: xout = relu(h)*sigmoid(g) + x*(1-sigmoid(g)), bf16.
__global__ __launch_bounds__(256)
void hwy_gemm(const unsigned short* __restrict__ xin, const unsigned short* __restrict__ WcT,
              const float* __restrict__ bh, const float* __restrict__ bg,
              unsigned short* __restrict__ xout) {
  __shared__ __align__(16) char As[128 * 128];
  __shared__ __align__(16) char Bs[128 * 128];   // rows 0-63: Wh^T n0+..; 64-127: Wg^T 512+n0+..
  const int tid  = threadIdx.x;
  const int lane = tid & 63;
  const int wave = tid >> 6;
  const int wm = wave >> 1, wn = wave & 1;
  const int m0 = blockIdx.y * 128;
  const int n0 = blockIdx.x * 64;

  const int sr = tid >> 1, sp = tid & 1;
  const unsigned short* arow16 = xin + (size_t)(m0 + sr) * HIDD;
  const int rb = tid >> 1;
  const int grow = (rb < 64) ? (n0 + rb) : (512 + n0 + rb - 64);
  const unsigned short* brow = WcT + (size_t)grow * HIDD;

  f32x4 acc[4][2][2];
  #pragma unroll
  for (int i = 0; i < 4; ++i)
    #pragma unroll
    for (int j = 0; j < 2; ++j)
      #pragma unroll
      for (int p = 0; p < 2; ++p) acc[i][j][p] = (f32x4){0.f, 0.f, 0.f, 0.f};

  u16x8 ar16[4], br16[4];

  auto LOADREGS = [&](int t) {
    int k0 = t * 64;
    #pragma unroll
    for (int j = 0; j < 4; ++j)
      ar16[j] = *(const u16x8*)(arow16 + k0 + (sp * 4 + j) * 8);
    #pragma unroll
    for (int q = 0; q < 4; ++q)
      br16[q] = *(const u16x8*)(brow + k0 + (sp * 4 + q) * 8);
  };
  auto WRITELDS = [&]() {
    #pragma unroll
    for (int j = 0; j < 4; ++j) {
      int gq = sp * 4 + j;
      *(u16x8*)(As + sr * 128 + ((gq ^ (sr & 7)) << 4)) = ar16[j];
    }
    #pragma unroll
    for (int q = 0; q < 4; ++q) {
      int gq = sp * 4 + q;
      *(u16x8*)(Bs + rb * 128 + ((gq ^ (rb & 7)) << 4)) = br16[q];
    }
  };

  for (int t = 0; t < 8; ++t) {
    if (t == 0) LOADREGS(0);
    else __syncthreads();
    WRITELDS();
    if (t + 1 < 8) LOADREGS(t + 1);
    __syncthreads();
    #pragma unroll
    for (int ks = 0; ks < 2; ++ks) {
      bf16x8 af[4]; bf16x8 bfr[2][2];
      int kg = ks * 4 + (lane >> 4);
      #pragma unroll
      for (int i = 0; i < 4; ++i) {
        int r = wm * 64 + i * 16 + (lane & 15);
        af[i] = *(const bf16x8*)(As + r * 128 + ((kg ^ (r & 7)) << 4));
      }
      #pragma unroll
      for (int j = 0; j < 2; ++j)
        #pragma unroll
        for (int p = 0; p < 2; ++p) {
          int n = p * 64 + wn * 32 + j * 16 + (lane & 15);
          bfr[j][p] = *(const bf16x8*)(Bs + n * 128 + ((kg ^ (n & 7)) << 4));
        }
      #pragma unroll
      for (int i = 0; i < 4; ++i)
        #pragma unroll
        for (int j = 0; j < 2; ++j)
          #pragma unroll
          for (int p = 0; p < 2; ++p)
            acc[i][j][p] = __builtin_amdgcn_mfma_f32_16x16x32_bf16(af[i], bfr[j][p], acc[i][j][p], 0, 0, 0);
    }
  }

  #pragma unroll
  for (int j = 0; j < 2; ++j) {
    int col = n0 + wn * 32 + j * 16 + (lane & 15);
    float bhv = bh[col], bgv = bg[col];
    #pragma unroll
    for (int i = 0; i < 4; ++i) {
      int row = m0 + wm * 64 + i * 16 + ((lane >> 4) << 2);
      #pragma unroll
      for (int rr = 0; rr < 4; ++rr) {
        float hv = fmaxf(acc[i][j][0][rr] + bhv, 0.f);
        float gv = acc[i][j][1][rr] + bgv;
        float tv = 1.f / (1.f + expf(-gv));
        float xi = bf2f(xin[(size_t)(row + rr) * HIDD + col]);
        xout[(size_t)(row + rr) * HIDD + col] = f2bf(hv * tv + xi * (1.f - tv));
      }
    }
  }
}

// per-pair combine through the dedup indirection:
// ex = relu(sum_q Ppart[q][newpos[idx_x[p]]]), ey likewise; xb = bf16((ex-ey)^2/sqrt(512))
__global__ void pair_combine(const float* __restrict__ P, const int* __restrict__ newpos,
                             const int* __restrict__ idxx, const int* __restrict__ idxy,
                             unsigned short* __restrict__ xb) {
  int i = blockIdx.x * 256 + threadIdx.x;   // 4096 pairs x 128 float4-cols
  int p = i >> 7, c = i & 127;
  int rx = newpos[idxx[p]];
  int ry = newpos[idxy[p]];
  const size_t qs = (size_t)8192 * 512 / 4;     // per-partial size in float4s
  const float4* Px = (const float4*)P + (size_t)rx * 128 + c;
  const float4* Py = (const float4*)P + (size_t)ry * 128 + c;
  float4 a = Px[0];
  float4 b = Py[0];
  #pragma unroll
  for (int q = 1; q < KSPLIT; ++q) {
    float4 aq = Px[q * qs]; float4 bq = Py[q * qs];
    a.x += aq.x; a.y += aq.y; a.z += aq.z; a.w += aq.w;
    b.x += bq.x; b.y += bq.y; b.z += bq.z; b.w += bq.w;
  }
  const float s = 0.04419417382415922f;    // 1/sqrt(512)
  float ex, ey, d;
  u16x4 o;
  ex = fmaxf(a.x, 0.f); ey = fmaxf(b.x, 0.f); d = ex - ey; o[0] = f2bf(d * d * s);
  ex = fmaxf(a.y, 0.f); ey = fmaxf(b.y, 0.f); d = ex - ey; o[1] = f2bf(d * d * s);
  ex = fmaxf(a.z, 0.f); ey = fmaxf(b.z, 0.f); d = ex - ey; o[2] = f2bf(d * d * s);
  ex = fmaxf(a.w, 0.f); ey = fmaxf(b.w, 0.f); d = ex - ey; o[3] = f2bf(d * d * s);
  ((u16x4*)xb)[i] = o;
}

// logits + 2-class log_softmax, one wave per row
__global__ void logits_lsm(const unsigned short* __restrict__ x2, const float* __restrict__ Wl,
                           const float* __restrict__ bl, float* __restrict__ out) {
  int gw = (blockIdx.x * blockDim.x + threadIdx.x) >> 6;
  int lane = threadIdx.x & 63;
  const unsigned short* xr = x2 + (size_t)gw * HIDD;
  u16x8 xv = *(const u16x8*)(xr + lane * 8);
  float4 w0 = ((const float4*)Wl)[lane * 4 + 0];
  float4 w1 = ((const float4*)Wl)[lane * 4 + 1];
  float4 w2 = ((const float4*)Wl)[lane * 4 + 2];
  float4 w3 = ((const float4*)Wl)[lane * 4 + 3];
  float xs[8];
  #pragma unroll
  for (int j = 0; j < 8; ++j) xs[j] = bf2f(xv[j]);
  float s0 = xs[0]*w0.x + xs[1]*w0.z + xs[2]*w1.x + xs[3]*w1.z
           + xs[4]*w2.x + xs[5]*w2.z + xs[6]*w3.x + xs[7]*w3.z;
  float s1 = xs[0]*w0.y + xs[1]*w0.w + xs[2]*w1.y + xs[3]*w1.w
           + xs[4]*w2.y + xs[5]*w2.w + xs[6]*w3.y + xs[7]*w3.w;
  #pragma unroll
  for (int off = 32; off; off >>= 1) { s0 += __shfl_down(s0, off); s1 += __shfl_down(s1, off); }
  if (lane == 0) {
    float l0 = s0 + bl[0], l1 = s1 + bl[1];
    float mx = fmaxf(l0, l1);
    float lse = mx + logf(expf(l0 - mx) + expf(l1 - mx));
    out[(size_t)gw * 2 + 0] = l0 - lse;
    out[(size_t)gw * 2 + 1] = l1 - lse;
  }
}

extern "C" void kernel_launch(void* const* d_in, const int* in_sizes, int n_in,
                              void* d_out, int out_size, void* d_ws, size_t ws_size,
                              hipStream_t stream) {
  const float* A   = (const float*)d_in[0];
  const float* W1  = (const float*)d_in[1];
  const float* Wh0 = (const float*)d_in[2];
  const float* bh0 = (const float*)d_in[3];
  const float* Wg0 = (const float*)d_in[4];
  const float* bg0 = (const float*)d_in[5];
  const float* Wh1 = (const float*)d_in[6];
  const float* bh1 = (const float*)d_in[7];
  const float* Wg1 = (const float*)d_in[8];
  const float* bg1 = (const float*)d_in[9];
  const float* Wl  = (const float*)d_in[10];
  const float* bl  = (const float*)d_in[11];
  const int* idxx  = (const int*)d_in[12];
  const int* idxy  = (const int*)d_in[13];
  float* out = (float*)d_out;

  char* w = (char*)d_ws;
  auto carve = [&](size_t bytes) { char* p = w; w += (bytes + 255) & ~(size_t)255; return p; };
  unsigned short* W1T  = (unsigned short*)carve((size_t)512 * KPAD * 2);
  unsigned short* WcT0 = (unsigned short*)carve((size_t)1024 * 512 * 2);
  unsigned short* WcT1 = (unsigned short*)carve((size_t)1024 * 512 * 2);
  float* Ppart         = (float*)carve((size_t)KSPLIT * 8192 * 512 * 4);
  unsigned short* xb0  = (unsigned short*)carve((size_t)4096 * 512 * 2);
  unsigned short* xb1  = (unsigned short*)carve((size_t)4096 * 512 * 2);
  unsigned short* xb2  = (unsigned short*)carve((size_t)4096 * 512 * 2);
  int* flags           = (int*)carve((size_t)KPAD * 4);
  int* newpos          = (int*)carve((size_t)KPAD * 4);
  int* rows            = (int*)carve((size_t)8256 * 4);
  int* nuniq           = (int*)carve(256);

  // dedup the gathered row set (idxx/idxy are 4096 entries EACH)
  zero_flags<<<dim3((KPAD + 255) / 256), 256, 0, stream>>>(flags);
  mark_rows<<<dim3(BP / 256), 256, 0, stream>>>(idxx, idxy, flags);
  scan_compact<<<dim3(1), 1024, 0, stream>>>(flags, newpos, rows, nuniq);

  // weight prep (~31 MB traffic, 2 launches)
  transpose_cvt<<<dim3(KPAD / 32, 16), 256, 0, stream>>>(W1, W1T, NN, KPAD);
  transpose_cvt4<<<dim3(16, 16, 4), 256, 0, stream>>>(
      Wh0, Wg0, Wh1, Wg1,
      WcT0, WcT0 + (size_t)512 * 512, WcT1, WcT1 + (size_t)512 * 512);

  // Ppart[ksp] = A[unique rows] @ W1 K-chunk; worst-case grid, early-exit beyond nuniq
  gather_gemm<<<dim3(KSPLIT, 128), 512, 0, stream>>>(A, W1T, Ppart, rows, nuniq);
  pair_combine<<<dim3(2048), 256, 0, stream>>>(Ppart, newpos, idxx, idxy, xb0);

  // fused highway layers
  hwy_gemm<<<dim3(8, 32), 256, 0, stream>>>(xb0, WcT0, bh0, bg0, xb1);
  hwy_gemm<<<dim3(8, 32), 256, 0, stream>>>(xb1, WcT1, bh1, bg1, xb2);

  logits_lsm<<<dim3(1024), 256, 0, stream>>>(xb2, Wl, bl, out);
}

// Round 9
// 169.412 us; speedup vs baseline: 1.2393x; 1.1588x over previous
//
#include <hip/hip_runtime.h>
#include <hip/hip_bf16.h>
#include <math.h>

#define NN    10000
#define HIDD  512
#define BP    4096
#define KPAD2 10112     // 79 * 128  (fp8 gather GEMM, BK=128)
#define NK2   79
#define KSPLIT 5
#define ASCALE 16.0f
#define BSCALE 64.0f
#define INVSC  0.0009765625f   // 1/(16*64)

typedef short bf16x8 __attribute__((ext_vector_type(8)));
typedef float f32x4  __attribute__((ext_vector_type(4)));
typedef unsigned short u16x4 __attribute__((ext_vector_type(4)));
typedef unsigned short u16x8 __attribute__((ext_vector_type(8)));
typedef int   i32x4  __attribute__((ext_vector_type(4)));

__device__ __forceinline__ unsigned short f2bf(float f) {
  union { float f; unsigned u; } v; v.f = f;
  unsigned r = v.u + 0x7FFFu + ((v.u >> 16) & 1u);   // RN-even
  return (unsigned short)(r >> 16);
}
__device__ __forceinline__ float bf2f(unsigned short u) {
  union { unsigned u; float f; } v; v.u = ((unsigned)u) << 16;
  return v.f;
}
__device__ __forceinline__ void gload_lds16(const void* g, void* l) {
  __builtin_amdgcn_global_load_lds((const __attribute__((address_space(1))) unsigned int*)g,
                                   (__attribute__((address_space(3))) unsigned int*)l, 16, 0, 0);
}

// pack 2 f32 -> 2 fp8 e4m3 into low (hi=false) or high (hi=true) 16 bits of `old`
__device__ __forceinline__ int f2fp8pair(float a, float b, int old, bool hi) {
#if __has_builtin(__builtin_amdgcn_cvt_pk_fp8_f32)
  return hi ? __builtin_amdgcn_cvt_pk_fp8_f32(a, b, old, true)
            : __builtin_amdgcn_cvt_pk_fp8_f32(a, b, old, false);
#else
  auto cv = [](float x) -> unsigned {
    float c = fminf(fmaxf(x, -448.f), 448.f);
    union { float f; unsigned u; } v; v.f = c;
    unsigned sign = (v.u >> 24) & 0x80u;
    unsigned absu = v.u & 0x7FFFFFFFu;
    if (absu < 0x3B800000u) {                 // |x| < 2^-8: subnormal region
      int q = (int)rintf(fabsf(c) * 512.f);   // units of 2^-9
      if (q > 7) q = 7;
      return sign | (unsigned)q;
    }
    unsigned r = absu + 0x00080000u + ((absu >> 20) & 1u);  // RNE at bit 20
    int e = (int)((r >> 23) & 0xFF) - 127;
    unsigned m = (r >> 20) & 7u;
    if (e > 8) return sign | 0x7Eu;
    if (e < -6) { int q = (int)rintf(fabsf(c) * 512.f); if (q > 7) q = 7; return sign | (unsigned)q; }
    return sign | ((unsigned)(e + 7) << 3) | m;
  };
  unsigned w = cv(a) | (cv(b) << 8);
  return hi ? ((old & 0xFFFF) | (int)(w << 16)) : (int)(((unsigned)old & 0xFFFF0000u) | w);
#endif
}

// ---- dedup: zero -> flags -> exclusive scan -> compact row list ----
__global__ void zero_flags(int* __restrict__ flags) {
  int i = blockIdx.x * 256 + threadIdx.x;
  if (i < KPAD2) flags[i] = 0;
}

__global__ void mark_rows(const int* __restrict__ idxx, const int* __restrict__ idxy,
                          int* __restrict__ flags) {
  int i = blockIdx.x * 256 + threadIdx.x;   // 0..4095 (B entries EACH)
  flags[idxx[i]] = 1;
  flags[idxy[i]] = 1;
}

__global__ __launch_bounds__(1024)
void scan_compact(const int* __restrict__ flags, int* __restrict__ newpos,
                  int* __restrict__ rows, int* __restrict__ nuniq) {
  __shared__ int part[1024];
  int t = threadIdx.x;
  int base = t * 10;
  int loc[10]; int s = 0;
  #pragma unroll
  for (int j = 0; j < 10; ++j) {
    int idx = base + j;
    int f = (idx < NN) ? flags[idx] : 0;
    loc[j] = s; s += f;
  }
  part[t] = s;
  __syncthreads();
  for (int off = 1; off < 1024; off <<= 1) {
    int v = (t >= off) ? part[t - off] : 0;
    __syncthreads();
    part[t] += v;
    __syncthreads();
  }
  int pre = (t == 0) ? 0 : part[t - 1];
  #pragma unroll
  for (int j = 0; j < 10; ++j) {
    int idx = base + j;
    if (idx < NN) {
      int pos = pre + loc[j];
      newpos[idx] = pos;
      if (flags[idx]) rows[pos] = idx;
    }
  }
  if (t == 1023) nuniq[0] = part[1023];
}

// W1 f32 [K][512] -> fp8 e4m3 (x BSCALE) [512][KPAD2], zero-padded k >= K
__global__ void transpose_cvt_fp8(const float* __restrict__ src, unsigned char* __restrict__ dst,
                                  int K) {
  __shared__ float tile[32][33];
  int k0 = blockIdx.x * 32, n0 = blockIdx.y * 32;
  int t = threadIdx.x, c = t & 31, r = t >> 5;
  #pragma unroll
  for (int i = 0; i < 4; ++i) {
    int k = k0 + r + i * 8;
    float v = (k < K) ? src[(size_t)k * 512 + (n0 + c)] : 0.f;
    tile[r + i * 8][c] = v;
  }
  __syncthreads();
  // write: 16 k-pairs (c2 = t&15) x 16 n (rn = t>>4), 2 passes over n
  int c2 = t & 15, rn = t >> 4;
  #pragma unroll
  for (int i = 0; i < 2; ++i) {
    int n = rn + i * 16;
    int w = f2fp8pair(tile[2 * c2][n] * BSCALE, tile[2 * c2 + 1][n] * BSCALE, 0, false);
    *(unsigned short*)(dst + (size_t)(n0 + n) * KPAD2 + k0 + 2 * c2) = (unsigned short)(w & 0xFFFF);
  }
}

// 4 x (512x512 transpose+cvt bf16) in one launch (highway weights)
__global__ void transpose_cvt4(const float* __restrict__ s0, const float* __restrict__ s1,
                               const float* __restrict__ s2, const float* __restrict__ s3,
                               unsigned short* __restrict__ d0, unsigned short* __restrict__ d1,
                               unsigned short* __restrict__ d2, unsigned short* __restrict__ d3) {
  __shared__ float tile[32][33];
  const float* src = (blockIdx.z == 0) ? s0 : (blockIdx.z == 1) ? s1 : (blockIdx.z == 2) ? s2 : s3;
  unsigned short* dst = (blockIdx.z == 0) ? d0 : (blockIdx.z == 1) ? d1 : (blockIdx.z == 2) ? d2 : d3;
  int k0 = blockIdx.x * 32, n0 = blockIdx.y * 32;
  int t = threadIdx.x, c = t & 31, r = t >> 5;
  #pragma unroll
  for (int i = 0; i < 4; ++i)
    tile[r + i * 8][c] = src[(size_t)(k0 + r + i * 8) * 512 + (n0 + c)];
  __syncthreads();
  #pragma unroll
  for (int i = 0; i < 4; ++i)
    dst[(size_t)(n0 + r + i * 8) * 512 + (k0 + c)] = f2bf(tile[c][r + i * 8]);
}

// FP8 Gather-GEMM: Ppart[ksp][row][512] = (A[rows]*16) @ (W1T*64)^T over K-chunk.
// Tile 64m x 512n x BK=128 fp8; 512 threads = 8 waves, wave-tile 64x64.
// LDS: As 8KB + Bs 64KB = 72KB -> 2 blocks/CU. LDS traffic per FLOP halved vs
// bf16 (8B fragments, ds_read_b64); MFMA per iteration doubled (K=128).
// Same 3-barrier schedule as the bf16 round-8 kernel (known-good).
__global__ __launch_bounds__(512, 4)
void gather_gemm(const float* __restrict__ A, const unsigned char* __restrict__ BT8,
                 float* __restrict__ Ppart,
                 const int* __restrict__ rows, const int* __restrict__ nuniq_p) {
  __shared__ __align__(16) char As[64 * 128];    // 64 rows x 128 fp8, XOR-swizzled 16B granules
  __shared__ __align__(16) char Bs[512 * 128];   // 512 n-rows x 128 fp8
  const int nuniq = nuniq_p[0];
  const int m0 = blockIdx.y * 64;
  if (m0 >= nuniq) return;
  const int tid  = threadIdx.x;
  const int lane = tid & 63;
  const int wave = tid >> 6;            // 0..7, owns n-range [wave*64, +64)
  const int ksp  = blockIdx.x;          // 0..KSPLIT-1
  const int t0   = (ksp * NK2) / KSPLIT;
  const int t1   = ((ksp + 1) * NK2) / KSPLIT;

  // A staging: 8 threads/row; thread covers 16 consecutive k (one 16B fp8 granule)
  const int sr = tid >> 3, sp = tid & 7;
  int m = m0 + sr;
  int g = rows[(m < nuniq) ? m : (nuniq - 1)];
  const float* arow = A + (size_t)g * NN;

  // B staging: per wave 8 gload_lds chunks of 1KB (8 rows of 128B); lane covers
  // row wave*64 + j*8 + (lane>>3), LDS 16B slot lane&7 <- global granule (lane&7)^(lane>>3)
  const unsigned char* bsrc0 =
      BT8 + (size_t)(wave * 64 + (lane >> 3)) * KPAD2 + (((lane & 7) ^ (lane >> 3)) << 4);
  char* bdst0 = Bs + (wave << 13);

  f32x4 acc[4][4];
  #pragma unroll
  for (int i = 0; i < 4; ++i)
    #pragma unroll
    for (int j = 0; j < 4; ++j) acc[i][j] = (f32x4){0.f, 0.f, 0.f, 0.f};

  float4 ar[4];

  auto LOADA = [&](int t) {
    int ka = t * 128 + sp * 16;
    if (ka < NN) {                      // granule boundary lands exactly at 10000
      #pragma unroll
      for (int j = 0; j < 4; ++j) ar[j] = *(const float4*)(arow + ka + j * 4);
    } else {
      #pragma unroll
      for (int j = 0; j < 4; ++j) ar[j] = make_float4(0.f, 0.f, 0.f, 0.f);
    }
  };
  auto ISSUEB = [&](int t) {
    const unsigned char* s = bsrc0 + (size_t)t * 128;
    #pragma unroll
    for (int j = 0; j < 8; ++j)
      gload_lds16(s + (size_t)j * 8 * KPAD2, bdst0 + j * 1024);
  };
  auto WRITEA = [&]() {
    i32x4 o;
    #pragma unroll
    for (int q = 0; q < 4; ++q) {
      int w = f2fp8pair(ar[q].x * ASCALE, ar[q].y * ASCALE, 0, false);
      w     = f2fp8pair(ar[q].z * ASCALE, ar[q].w * ASCALE, w, true);
      o[q] = w;
    }
    *(i32x4*)(As + sr * 128 + ((sp ^ (sr & 7)) << 4)) = o;
  };

  LOADA(t0);
  ISSUEB(t0);
  for (int t = t0; t < t1; ++t) {
    if (t > t0) __syncthreads();      // drains B(t) gloads; As writable again
    WRITEA();                         // compiler waits A(t) regs
    __syncthreads();                  // As(t), Bs(t) visible to all
    if (t + 1 < t1) LOADA(t + 1);     // A prefetch rides under compute
    #pragma unroll
    for (int ks = 0; ks < 4; ++ks) {  // 4 x K=32 sections of the 128B row
      int kq  = lane >> 4;            // k-quarter within section
      int G   = ks * 2 + (kq >> 1);   // 16B granule index 0..7
      int inn = (kq & 1) << 3;        // 8B half within granule
      long aL[4]; long bL[4];
      #pragma unroll
      for (int i = 0; i < 4; ++i) {
        int r = i * 16 + (lane & 15);
        aL[i] = *(const long*)(As + r * 128 + ((G ^ (r & 7)) << 4) + inn);
      }
      #pragma unroll
      for (int j = 0; j < 4; ++j) {
        int n = wave * 64 + j * 16 + (lane & 15);
        bL[j] = *(const long*)(Bs + n * 128 + ((G ^ (n & 7)) << 4) + inn);
      }
      #pragma unroll
      for (int i = 0; i < 4; ++i)
        #pragma unroll
        for (int j = 0; j < 4; ++j)
          acc[i][j] = __builtin_amdgcn_mfma_f32_16x16x32_fp8_fp8(aL[i], bL[j], acc[i][j], 0, 0, 0);
    }
    __syncthreads();                  // all waves done reading LDS(t)
    if (t + 1 < t1) ISSUEB(t + 1);    // refill Bs for next iter
  }

  float* Cb = Ppart + (size_t)ksp * (8192 * 512);
  #pragma unroll
  for (int i = 0; i < 4; ++i) {
    #pragma unroll
    for (int j = 0; j < 4; ++j) {
      int row = m0 + i * 16 + ((lane >> 4) << 2);
      int col = wave * 64 + j * 16 + (lane & 15);
      #pragma unroll
      for (int rr = 0; rr < 4; ++rr)
        Cb[(size_t)(row + rr) * 512 + col] = acc[i][j][rr];
    }
  }
}

// Fused highway layer (bf16): h = x@Wh + bh, g = x@Wg + bg in one tile pass;
// epilogue: xout = relu(h)*sigmoid(g) + x*(1-sigmoid(g)).
__global__ __launch_bounds__(256)
void hwy_gemm(const unsigned short* __restrict__ xin, const unsigned short* __restrict__ WcT,
              const float* __restrict__ bh, const float* __restrict__ bg,
              unsigned short* __restrict__ xout) {
  __shared__ __align__(16) char As[128 * 128];
  __shared__ __align__(16) char Bs[128 * 128];
  const int tid  = threadIdx.x;
  const int lane = tid & 63;
  const int wave = tid >> 6;
  const int wm = wave >> 1, wn = wave & 1;
  const int m0 = blockIdx.y * 128;
  const int n0 = blockIdx.x * 64;

  const int sr = tid >> 1, sp = tid & 1;
  const unsigned short* arow16 = xin + (size_t)(m0 + sr) * HIDD;
  const int rb = tid >> 1;
  const int grow = (rb < 64) ? (n0 + rb) : (512 + n0 + rb - 64);
  const unsigned short* brow = WcT + (size_t)grow * HIDD;

  f32x4 acc[4][2][2];
  #pragma unroll
  for (int i = 0; i < 4; ++i)
    #pragma unroll
    for (int j = 0; j < 2; ++j)
      #pragma unroll
      for (int p = 0; p < 2; ++p) acc[i][j][p] = (f32x4){0.f, 0.f, 0.f, 0.f};

  u16x8 ar16[4], br16[4];

  auto LOADREGS = [&](int t) {
    int k0 = t * 64;
    #pragma unroll
    for (int j = 0; j < 4; ++j)
      ar16[j] = *(const u16x8*)(arow16 + k0 + (sp * 4 + j) * 8);
    #pragma unroll
    for (int q = 0; q < 4; ++q)
      br16[q] = *(const u16x8*)(brow + k0 + (sp * 4 + q) * 8);
  };
  auto WRITELDS = [&]() {
    #pragma unroll
    for (int j = 0; j < 4; ++j) {
      int gq = sp * 4 + j;
      *(u16x8*)(As + sr * 128 + ((gq ^ (sr & 7)) << 4)) = ar16[j];
    }
    #pragma unroll
    for (int q = 0; q < 4; ++q) {
      int gq = sp * 4 + q;
      *(u16x8*)(Bs + rb * 128 + ((gq ^ (rb & 7)) << 4)) = br16[q];
    }
  };

  for (int t = 0; t < 8; ++t) {
    if (t == 0) LOADREGS(0);
    else __syncthreads();
    WRITELDS();
    if (t + 1 < 8) LOADREGS(t + 1);
    __syncthreads();
    #pragma unroll
    for (int ks = 0; ks < 2; ++ks) {
      bf16x8 af[4]; bf16x8 bfr[2][2];
      int kg = ks * 4 + (lane >> 4);
      #pragma unroll
      for (int i = 0; i < 4; ++i) {
        int r = wm * 64 + i * 16 + (lane & 15);
        af[i] = *(const bf16x8*)(As + r * 128 + ((kg ^ (r & 7)) << 4));
      }
      #pragma unroll
      for (int j = 0; j < 2; ++j)
        #pragma unroll
        for (int p = 0; p < 2; ++p) {
          int n = p * 64 + wn * 32 + j * 16 + (lane & 15);
          bfr[j][p] = *(const bf16x8*)(Bs + n * 128 + ((kg ^ (n & 7)) << 4));
        }
      #pragma unroll
      for (int i = 0; i < 4; ++i)
        #pragma unroll
        for (int j = 0; j < 2; ++j)
          #pragma unroll
          for (int p = 0; p < 2; ++p)
            acc[i][j][p] = __builtin_amdgcn_mfma_f32_16x16x32_bf16(af[i], bfr[j][p], acc[i][j][p], 0, 0, 0);
    }
  }

  #pragma unroll
  for (int j = 0; j < 2; ++j) {
    int col = n0 + wn * 32 + j * 16 + (lane & 15);
    float bhv = bh[col], bgv = bg[col];
    #pragma unroll
    for (int i = 0; i < 4; ++i) {
      int row = m0 + wm * 64 + i * 16 + ((lane >> 4) << 2);
      #pragma unroll
      for (int rr = 0; rr < 4; ++rr) {
        float hv = fmaxf(acc[i][j][0][rr] + bhv, 0.f);
        float gv = acc[i][j][1][rr] + bgv;
        float tv = 1.f / (1.f + expf(-gv));
        float xi = bf2f(xin[(size_t)(row + rr) * HIDD + col]);
        xout[(size_t)(row + rr) * HIDD + col] = f2bf(hv * tv + xi * (1.f - tv));
      }
    }
  }
}

// per-pair combine through the dedup indirection; descale (1/1024) before relu.
__global__ void pair_combine(const float* __restrict__ P, const int* __restrict__ newpos,
                             const int* __restrict__ idxx, const int* __restrict__ idxy,
                             unsigned short* __restrict__ xb) {
  int i = blockIdx.x * 256 + threadIdx.x;   // 4096 pairs x 128 float4-cols
  int p = i >> 7, c = i & 127;
  int rx = newpos[idxx[p]];
  int ry = newpos[idxy[p]];
  const size_t qs = (size_t)8192 * 512 / 4;
  const float4* Px = (const float4*)P + (size_t)rx * 128 + c;
  const float4* Py = (const float4*)P + (size_t)ry * 128 + c;
  float4 a = Px[0];
  float4 b = Py[0];
  #pragma unroll
  for (int q = 1; q < KSPLIT; ++q) {
    float4 aq = Px[q * qs]; float4 bq = Py[q * qs];
    a.x += aq.x; a.y += aq.y; a.z += aq.z; a.w += aq.w;
    b.x += bq.x; b.y += bq.y; b.z += bq.z; b.w += bq.w;
  }
  const float s = 0.04419417382415922f;    // 1/sqrt(512)
  float ex, ey, d;
  u16x4 o;
  ex = fmaxf(a.x * INVSC, 0.f); ey = fmaxf(b.x * INVSC, 0.f); d = ex - ey; o[0] = f2bf(d * d * s);
  ex = fmaxf(a.y * INVSC, 0.f); ey = fmaxf(b.y * INVSC, 0.f); d = ex - ey; o[1] = f2bf(d * d * s);
  ex = fmaxf(a.z * INVSC, 0.f); ey = fmaxf(b.z * INVSC, 0.f); d = ex - ey; o[2] = f2bf(d * d * s);
  ex = fmaxf(a.w * INVSC, 0.f); ey = fmaxf(b.w * INVSC, 0.f); d = ex - ey; o[3] = f2bf(d * d * s);
  ((u16x4*)xb)[i] = o;
}

// logits + 2-class log_softmax, one wave per row
__global__ void logits_lsm(const unsigned short* __restrict__ x2, const float* __restrict__ Wl,
                           const float* __restrict__ bl, float* __restrict__ out) {
  int gw = (blockIdx.x * blockDim.x + threadIdx.x) >> 6;
  int lane = threadIdx.x & 63;
  const unsigned short* xr = x2 + (size_t)gw * HIDD;
  u16x8 xv = *(const u16x8*)(xr + lane * 8);
  float4 w0 = ((const float4*)Wl)[lane * 4 + 0];
  float4 w1 = ((const float4*)Wl)[lane * 4 + 1];
  float4 w2 = ((const float4*)Wl)[lane * 4 + 2];
  float4 w3 = ((const float4*)Wl)[lane * 4 + 3];
  float xs[8];
  #pragma unroll
  for (int j = 0; j < 8; ++j) xs[j] = bf2f(xv[j]);
  float s0 = xs[0]*w0.x + xs[1]*w0.z + xs[2]*w1.x + xs[3]*w1.z
           + xs[4]*w2.x + xs[5]*w2.z + xs[6]*w3.x + xs[7]*w3.z;
  float s1 = xs[0]*w0.y + xs[1]*w0.w + xs[2]*w1.y + xs[3]*w1.w
           + xs[4]*w2.y + xs[5]*w2.w + xs[6]*w3.y + xs[7]*w3.w;
  #pragma unroll
  for (int off = 32; off; off >>= 1) { s0 += __shfl_down(s0, off); s1 += __shfl_down(s1, off); }
  if (lane == 0) {
    float l0 = s0 + bl[0], l1 = s1 + bl[1];
    float mx = fmaxf(l0, l1);
    float lse = mx + logf(expf(l0 - mx) + expf(l1 - mx));
    out[(size_t)gw * 2 + 0] = l0 - lse;
    out[(size_t)gw * 2 + 1] = l1 - lse;
  }
}

extern "C" void kernel_launch(void* const* d_in, const int* in_sizes, int n_in,
                              void* d_out, int out_size, void* d_ws, size_t ws_size,
                              hipStream_t stream) {
  const float* A   = (const float*)d_in[0];
  const float* W1  = (const float*)d_in[1];
  const float* Wh0 = (const float*)d_in[2];
  const float* bh0 = (const float*)d_in[3];
  const float* Wg0 = (const float*)d_in[4];
  const float* bg0 = (const float*)d_in[5];
  const float* Wh1 = (const float*)d_in[6];
  const float* bh1 = (const float*)d_in[7];
  const float* Wg1 = (const float*)d_in[8];
  const float* bg1 = (const float*)d_in[9];
  const float* Wl  = (const float*)d_in[10];
  const float* bl  = (const float*)d_in[11];
  const int* idxx  = (const int*)d_in[12];
  const int* idxy  = (const int*)d_in[13];
  float* out = (float*)d_out;

  char* w = (char*)d_ws;
  auto carve = [&](size_t bytes) { char* p = w; w += (bytes + 255) & ~(size_t)255; return p; };
  unsigned char* W1T8  = (unsigned char*)carve((size_t)512 * KPAD2);
  unsigned short* WcT0 = (unsigned short*)carve((size_t)1024 * 512 * 2);
  unsigned short* WcT1 = (unsigned short*)carve((size_t)1024 * 512 * 2);
  float* Ppart         = (float*)carve((size_t)KSPLIT * 8192 * 512 * 4);
  unsigned short* xb0  = (unsigned short*)carve((size_t)4096 * 512 * 2);
  unsigned short* xb1  = (unsigned short*)carve((size_t)4096 * 512 * 2);
  unsigned short* xb2  = (unsigned short*)carve((size_t)4096 * 512 * 2);
  int* flags           = (int*)carve((size_t)KPAD2 * 4);
  int* newpos          = (int*)carve((size_t)KPAD2 * 4);
  int* rows            = (int*)carve((size_t)8256 * 4);
  int* nuniq           = (int*)carve(256);

  // dedup the gathered row set
  zero_flags<<<dim3((KPAD2 + 255) / 256), 256, 0, stream>>>(flags);
  mark_rows<<<dim3(BP / 256), 256, 0, stream>>>(idxx, idxy, flags);
  scan_compact<<<dim3(1), 1024, 0, stream>>>(flags, newpos, rows, nuniq);

  // weight prep: W1 -> fp8 (x64), highway weights -> bf16
  transpose_cvt_fp8<<<dim3(KPAD2 / 32, 16), 256, 0, stream>>>(W1, W1T8, NN);
  transpose_cvt4<<<dim3(16, 16, 4), 256, 0, stream>>>(
      Wh0, Wg0, Wh1, Wg1,
      WcT0, WcT0 + (size_t)512 * 512, WcT1, WcT1 + (size_t)512 * 512);

  // Ppart[ksp] = (A[unique rows]*16) @ (W1*64) K-chunk (fp8, BK=128)
  gather_gemm<<<dim3(KSPLIT, 128), 512, 0, stream>>>(A, W1T8, Ppart, rows, nuniq);
  pair_combine<<<dim3(2048), 256, 0, stream>>>(Ppart, newpos, idxx, idxy, xb0);

  // fused highway layers
  hwy_gemm<<<dim3(8, 32), 256, 0, stream>>>(xb0, WcT0, bh0, bg0, xb1);
  hwy_gemm<<<dim3(8, 32), 256, 0, stream>>>(xb1, WcT1, bh1, bg1, xb2);

  logits_lsm<<<dim3(1024), 256, 0, stream>>>(xb2, Wl, bl, out);
}

// Round 10
// 146.008 us; speedup vs baseline: 1.4379x; 1.1603x over previous
//
#include <hip/hip_runtime.h>
#include <hip/hip_bf16.h>
#include <math.h>

#define NN    10000
#define HIDD  512
#define BP    4096
#define KPAD2 10112     // 79 * 128  (fp8 gather GEMM, BK=128)
#define NK2   79
#define KSPLIT 5
#define ASCALE 16.0f
#define BSCALE 64.0f
#define INVSC  0.0009765625f   // 1/(16*64)

typedef short bf16x8 __attribute__((ext_vector_type(8)));
typedef float f32x4  __attribute__((ext_vector_type(4)));
typedef unsigned short u16x4 __attribute__((ext_vector_type(4)));
typedef unsigned short u16x8 __attribute__((ext_vector_type(8)));
typedef int   i32x4  __attribute__((ext_vector_type(4)));

__device__ __forceinline__ unsigned short f2bf(float f) {
  union { float f; unsigned u; } v; v.f = f;
  unsigned r = v.u + 0x7FFFu + ((v.u >> 16) & 1u);   // RN-even
  return (unsigned short)(r >> 16);
}
__device__ __forceinline__ float bf2f(unsigned short u) {
  union { unsigned u; float f; } v; v.u = ((unsigned)u) << 16;
  return v.f;
}
__device__ __forceinline__ void gload_lds16(const void* g, void* l) {
  __builtin_amdgcn_global_load_lds((const __attribute__((address_space(1))) unsigned int*)g,
                                   (__attribute__((address_space(3))) unsigned int*)l, 16, 0, 0);
}

// pack 2 f32 -> 2 fp8 e4m3 into low (hi=false) or high (hi=true) 16 bits of `old`
__device__ __forceinline__ int f2fp8pair(float a, float b, int old, bool hi) {
#if __has_builtin(__builtin_amdgcn_cvt_pk_fp8_f32)
  return hi ? __builtin_amdgcn_cvt_pk_fp8_f32(a, b, old, true)
            : __builtin_amdgcn_cvt_pk_fp8_f32(a, b, old, false);
#else
  auto cv = [](float x) -> unsigned {
    float c = fminf(fmaxf(x, -448.f), 448.f);
    union { float f; unsigned u; } v; v.f = c;
    unsigned sign = (v.u >> 24) & 0x80u;
    unsigned absu = v.u & 0x7FFFFFFFu;
    if (absu < 0x3B800000u) {
      int q = (int)rintf(fabsf(c) * 512.f);
      if (q > 7) q = 7;
      return sign | (unsigned)q;
    }
    unsigned r = absu + 0x00080000u + ((absu >> 20) & 1u);
    int e = (int)((r >> 23) & 0xFF) - 127;
    unsigned m = (r >> 20) & 7u;
    if (e > 8) return sign | 0x7Eu;
    if (e < -6) { int q = (int)rintf(fabsf(c) * 512.f); if (q > 7) q = 7; return sign | (unsigned)q; }
    return sign | ((unsigned)(e + 7) << 3) | m;
  };
  unsigned w = cv(a) | (cv(b) << 8);
  return hi ? ((old & 0xFFFF) | (int)(w << 16)) : (int)(((unsigned)old & 0xFFFF0000u) | w);
#endif
}

// ---- single-kernel dedup: LDS byte flags -> mark -> scan -> compact ----
__global__ __launch_bounds__(1024)
void dedup_all(const int* __restrict__ idxx, const int* __restrict__ idxy,
               int* __restrict__ newpos, int* __restrict__ rows, int* __restrict__ nuniq) {
  __shared__ unsigned char flag[10240];
  __shared__ int part[1024];
  int t = threadIdx.x;
  // zero flags (10240 B = 2560 ints)
  #pragma unroll
  for (int j = 0; j < 3; ++j) {
    int w = t + j * 1024;
    if (w < 2560) ((int*)flag)[w] = 0;
  }
  __syncthreads();
  // mark: 4096 entries each array -> 4 per thread from each
  #pragma unroll
  for (int j = 0; j < 4; ++j) {
    flag[idxx[t + j * 1024]] = 1;
    flag[idxy[t + j * 1024]] = 1;
  }
  __syncthreads();
  // scan: 10 elements/thread
  int base = t * 10;
  int loc[10]; int s = 0;
  #pragma unroll
  for (int j = 0; j < 10; ++j) {
    int f = (base + j < NN) ? (int)flag[base + j] : 0;
    loc[j] = s; s += f;
  }
  part[t] = s;
  __syncthreads();
  for (int off = 1; off < 1024; off <<= 1) {
    int v = (t >= off) ? part[t - off] : 0;
    __syncthreads();
    part[t] += v;
    __syncthreads();
  }
  int pre = (t == 0) ? 0 : part[t - 1];
  #pragma unroll
  for (int j = 0; j < 10; ++j) {
    int idx = base + j;
    if (idx < NN) {
      int pos = pre + loc[j];
      newpos[idx] = pos;
      if (flag[idx]) rows[pos] = idx;
    }
  }
  if (t == 1023) nuniq[0] = part[1023];
}

// Merged weight prep (flattened 1-D grid, 256 threads):
//  bid < 5056            : W1 f32 [NN][512] -> fp8 e4m3 (x BSCALE) [512][KPAD2]
//  bid >= 5056 (1024 bl) : 4x 512x512 transpose+cvt bf16 (highway weights)
__global__ void prep_weights(const float* __restrict__ W1, unsigned char* __restrict__ W1T8,
                             const float* __restrict__ s0, const float* __restrict__ s1,
                             const float* __restrict__ s2, const float* __restrict__ s3,
                             unsigned short* __restrict__ d0, unsigned short* __restrict__ d1,
                             unsigned short* __restrict__ d2, unsigned short* __restrict__ d3) {
  __shared__ float tile[32][33];
  int bid = blockIdx.x;
  int t = threadIdx.x, c = t & 31, r = t >> 5;
  if (bid < 5056) {                       // W1 -> fp8: 316 k-tiles x 16 n-tiles
    int k0 = (bid % 316) * 32, n0 = (bid / 316) * 32;
    #pragma unroll
    for (int i = 0; i < 4; ++i) {
      int k = k0 + r + i * 8;
      tile[r + i * 8][c] = (k < NN) ? W1[(size_t)k * 512 + (n0 + c)] : 0.f;
    }
    __syncthreads();
    int c2 = t & 15, rn = t >> 4;
    #pragma unroll
    for (int i = 0; i < 2; ++i) {
      int n = rn + i * 16;
      int w = f2fp8pair(tile[2 * c2][n] * BSCALE, tile[2 * c2 + 1][n] * BSCALE, 0, false);
      *(unsigned short*)(W1T8 + (size_t)(n0 + n) * KPAD2 + k0 + 2 * c2) = (unsigned short)(w & 0xFFFF);
    }
  } else {                                // highway weights -> bf16 transpose
    int q = bid - 5056;
    int wsel = q >> 8, rr2 = q & 255;
    const float* src = (wsel == 0) ? s0 : (wsel == 1) ? s1 : (wsel == 2) ? s2 : s3;
    unsigned short* dst = (wsel == 0) ? d0 : (wsel == 1) ? d1 : (wsel == 2) ? d2 : d3;
    int k0 = (rr2 & 15) * 32, n0 = (rr2 >> 4) * 32;
    #pragma unroll
    for (int i = 0; i < 4; ++i)
      tile[r + i * 8][c] = src[(size_t)(k0 + r + i * 8) * 512 + (n0 + c)];
    __syncthreads();
    #pragma unroll
    for (int i = 0; i < 4; ++i)
      dst[(size_t)(n0 + r + i * 8) * 512 + (k0 + c)] = f2bf(tile[c][r + i * 8]);
  }
}

// FP8 Gather-GEMM: Ppart[ksp][row][512] (bf16) = (A[rows]*16) @ (W1T*64)^T over K-chunk.
// Tile 64m x 512n x BK=128 fp8; 512 threads = 8 waves, wave-tile 64x64; 72 KB LDS,
// 2 blocks/CU; same 3-barrier schedule as round 9 (known-good). Partials in bf16.
__global__ __launch_bounds__(512, 4)
void gather_gemm(const float* __restrict__ A, const unsigned char* __restrict__ BT8,
                 unsigned short* __restrict__ Ppart,
                 const int* __restrict__ rows, const int* __restrict__ nuniq_p) {
  __shared__ __align__(16) char As[64 * 128];
  __shared__ __align__(16) char Bs[512 * 128];
  const int nuniq = nuniq_p[0];
  const int m0 = blockIdx.y * 64;
  if (m0 >= nuniq) return;
  const int tid  = threadIdx.x;
  const int lane = tid & 63;
  const int wave = tid >> 6;
  const int ksp  = blockIdx.x;
  const int t0   = (ksp * NK2) / KSPLIT;
  const int t1   = ((ksp + 1) * NK2) / KSPLIT;

  const int sr = tid >> 3, sp = tid & 7;
  int m = m0 + sr;
  int g = rows[(m < nuniq) ? m : (nuniq - 1)];
  const float* arow = A + (size_t)g * NN;

  const unsigned char* bsrc0 =
      BT8 + (size_t)(wave * 64 + (lane >> 3)) * KPAD2 + (((lane & 7) ^ (lane >> 3)) << 4);
  char* bdst0 = Bs + (wave << 13);

  f32x4 acc[4][4];
  #pragma unroll
  for (int i = 0; i < 4; ++i)
    #pragma unroll
    for (int j = 0; j < 4; ++j) acc[i][j] = (f32x4){0.f, 0.f, 0.f, 0.f};

  float4 ar[4];

  auto LOADA = [&](int t) {
    int ka = t * 128 + sp * 16;
    if (ka < NN) {
      #pragma unroll
      for (int j = 0; j < 4; ++j) ar[j] = *(const float4*)(arow + ka + j * 4);
    } else {
      #pragma unroll
      for (int j = 0; j < 4; ++j) ar[j] = make_float4(0.f, 0.f, 0.f, 0.f);
    }
  };
  auto ISSUEB = [&](int t) {
    const unsigned char* s = bsrc0 + (size_t)t * 128;
    #pragma unroll
    for (int j = 0; j < 8; ++j)
      gload_lds16(s + (size_t)j * 8 * KPAD2, bdst0 + j * 1024);
  };
  auto WRITEA = [&]() {
    i32x4 o;
    #pragma unroll
    for (int q = 0; q < 4; ++q) {
      int w = f2fp8pair(ar[q].x * ASCALE, ar[q].y * ASCALE, 0, false);
      w     = f2fp8pair(ar[q].z * ASCALE, ar[q].w * ASCALE, w, true);
      o[q] = w;
    }
    *(i32x4*)(As + sr * 128 + ((sp ^ (sr & 7)) << 4)) = o;
  };

  LOADA(t0);
  ISSUEB(t0);
  for (int t = t0; t < t1; ++t) {
    if (t > t0) __syncthreads();
    WRITEA();
    __syncthreads();
    if (t + 1 < t1) LOADA(t + 1);
    #pragma unroll
    for (int ks = 0; ks < 4; ++ks) {
      int kq  = lane >> 4;
      int G   = ks * 2 + (kq >> 1);
      int inn = (kq & 1) << 3;
      long aL[4]; long bL[4];
      #pragma unroll
      for (int i = 0; i < 4; ++i) {
        int r = i * 16 + (lane & 15);
        aL[i] = *(const long*)(As + r * 128 + ((G ^ (r & 7)) << 4) + inn);
      }
      #pragma unroll
      for (int j = 0; j < 4; ++j) {
        int n = wave * 64 + j * 16 + (lane & 15);
        bL[j] = *(const long*)(Bs + n * 128 + ((G ^ (n & 7)) << 4) + inn);
      }
      #pragma unroll
      for (int i = 0; i < 4; ++i)
        #pragma unroll
        for (int j = 0; j < 4; ++j)
          acc[i][j] = __builtin_amdgcn_mfma_f32_16x16x32_fp8_fp8(aL[i], bL[j], acc[i][j], 0, 0, 0);
    }
    __syncthreads();
    if (t + 1 < t1) ISSUEB(t + 1);
  }

  unsigned short* Cb = Ppart + (size_t)ksp * (8192 * 512);
  #pragma unroll
  for (int i = 0; i < 4; ++i) {
    #pragma unroll
    for (int j = 0; j < 4; ++j) {
      int row = m0 + i * 16 + ((lane >> 4) << 2);
      int col = wave * 64 + j * 16 + (lane & 15);
      #pragma unroll
      for (int rr = 0; rr < 4; ++rr)
        Cb[(size_t)(row + rr) * 512 + col] = f2bf(acc[i][j][rr]);
    }
  }
}

// Fused highway layer (bf16)
__global__ __launch_bounds__(256)
void hwy_gemm(const unsigned short* __restrict__ xin, const unsigned short* __restrict__ WcT,
              const float* __restrict__ bh, const float* __restrict__ bg,
              unsigned short* __restrict__ xout) {
  __shared__ __align__(16) char As[128 * 128];
  __shared__ __align__(16) char Bs[128 * 128];
  const int tid  = threadIdx.x;
  const int lane = tid & 63;
  const int wave = tid >> 6;
  const int wm = wave >> 1, wn = wave & 1;
  const int m0 = blockIdx.y * 128;
  const int n0 = blockIdx.x * 64;

  const int sr = tid >> 1, sp = tid & 1;
  const unsigned short* arow16 = xin + (size_t)(m0 + sr) * HIDD;
  const int rb = tid >> 1;
  const int grow = (rb < 64) ? (n0 + rb) : (512 + n0 + rb - 64);
  const unsigned short* brow = WcT + (size_t)grow * HIDD;

  f32x4 acc[4][2][2];
  #pragma unroll
  for (int i = 0; i < 4; ++i)
    #pragma unroll
    for (int j = 0; j < 2; ++j)
      #pragma unroll
      for (int p = 0; p < 2; ++p) acc[i][j][p] = (f32x4){0.f, 0.f, 0.f, 0.f};

  u16x8 ar16[4], br16[4];

  auto LOADREGS = [&](int t) {
    int k0 = t * 64;
    #pragma unroll
    for (int j = 0; j < 4; ++j)
      ar16[j] = *(const u16x8*)(arow16 + k0 + (sp * 4 + j) * 8);
    #pragma unroll
    for (int q = 0; q < 4; ++q)
      br16[q] = *(const u16x8*)(brow + k0 + (sp * 4 + q) * 8);
  };
  auto WRITELDS = [&]() {
    #pragma unroll
    for (int j = 0; j < 4; ++j) {
      int gq = sp * 4 + j;
      *(u16x8*)(As + sr * 128 + ((gq ^ (sr & 7)) << 4)) = ar16[j];
    }
    #pragma unroll
    for (int q = 0; q < 4; ++q) {
      int gq = sp * 4 + q;
      *(u16x8*)(Bs + rb * 128 + ((gq ^ (rb & 7)) << 4)) = br16[q];
    }
  };

  for (int t = 0; t < 8; ++t) {
    if (t == 0) LOADREGS(0);
    else __syncthreads();
    WRITELDS();
    if (t + 1 < 8) LOADREGS(t + 1);
    __syncthreads();
    #pragma unroll
    for (int ks = 0; ks < 2; ++ks) {
      bf16x8 af[4]; bf16x8 bfr[2][2];
      int kg = ks * 4 + (lane >> 4);
      #pragma unroll
      for (int i = 0; i < 4; ++i) {
        int r = wm * 64 + i * 16 + (lane & 15);
        af[i] = *(const bf16x8*)(As + r * 128 + ((kg ^ (r & 7)) << 4));
      }
      #pragma unroll
      for (int j = 0; j < 2; ++j)
        #pragma unroll
        for (int p = 0; p < 2; ++p) {
          int n = p * 64 + wn * 32 + j * 16 + (lane & 15);
          bfr[j][p] = *(const bf16x8*)(Bs + n * 128 + ((kg ^ (n & 7)) << 4));
        }
      #pragma unroll
      for (int i = 0; i < 4; ++i)
        #pragma unroll
        for (int j = 0; j < 2; ++j)
          #pragma unroll
          for (int p = 0; p < 2; ++p)
            acc[i][j][p] = __builtin_amdgcn_mfma_f32_16x16x32_bf16(af[i], bfr[j][p], acc[i][j][p], 0, 0, 0);
    }
  }

  #pragma unroll
  for (int j = 0; j < 2; ++j) {
    int col = n0 + wn * 32 + j * 16 + (lane & 15);
    float bhv = bh[col], bgv = bg[col];
    #pragma unroll
    for (int i = 0; i < 4; ++i) {
      int row = m0 + wm * 64 + i * 16 + ((lane >> 4) << 2);
      #pragma unroll
      for (int rr = 0; rr < 4; ++rr) {
        float hv = fmaxf(acc[i][j][0][rr] + bhv, 0.f);
        float gv = acc[i][j][1][rr] + bgv;
        float tv = 1.f / (1.f + expf(-gv));
        float xi = bf2f(xin[(size_t)(row + rr) * HIDD + col]);
        xout[(size_t)(row + rr) * HIDD + col] = f2bf(hv * tv + xi * (1.f - tv));
      }
    }
  }
}

// per-pair combine (bf16 partials, u16x8 vectors); descale before relu.
__global__ void pair_combine(const unsigned short* __restrict__ P, const int* __restrict__ newpos,
                             const int* __restrict__ idxx, const int* __restrict__ idxy,
                             unsigned short* __restrict__ xb) {
  int i = blockIdx.x * 256 + threadIdx.x;   // 4096 pairs x 64 col-groups (8 cols each)
  int p = i >> 6, c = i & 63;
  int rx = newpos[idxx[p]];
  int ry = newpos[idxy[p]];
  const size_t qs = (size_t)8192 * 512;
  const unsigned short* Px = P + (size_t)rx * 512 + c * 8;
  const unsigned short* Py = P + (size_t)ry * 512 + c * 8;
  float ax[8], ay[8];
  #pragma unroll
  for (int j = 0; j < 8; ++j) { ax[j] = 0.f; ay[j] = 0.f; }
  #pragma unroll
  for (int q = 0; q < KSPLIT; ++q) {
    u16x8 vx = *(const u16x8*)(Px + q * qs);
    u16x8 vy = *(const u16x8*)(Py + q * qs);
    #pragma unroll
    for (int j = 0; j < 8; ++j) { ax[j] += bf2f(vx[j]); ay[j] += bf2f(vy[j]); }
  }
  const float s = 0.04419417382415922f;    // 1/sqrt(512)
  u16x8 o;
  #pragma unroll
  for (int j = 0; j < 8; ++j) {
    float ex = fmaxf(ax[j] * INVSC, 0.f);
    float ey = fmaxf(ay[j] * INVSC, 0.f);
    float d = ex - ey;
    o[j] = f2bf(d * d * s);
  }
  *(u16x8*)(xb + (size_t)i * 8) = o;
}

// logits + 2-class log_softmax, one wave per row
__global__ void logits_lsm(const unsigned short* __restrict__ x2, const float* __restrict__ Wl,
                           const float* __restrict__ bl, float* __restrict__ out) {
  int gw = (blockIdx.x * blockDim.x + threadIdx.x) >> 6;
  int lane = threadIdx.x & 63;
  const unsigned short* xr = x2 + (size_t)gw * HIDD;
  u16x8 xv = *(const u16x8*)(xr + lane * 8);
  float4 w0 = ((const float4*)Wl)[lane * 4 + 0];
  float4 w1 = ((const float4*)Wl)[lane * 4 + 1];
  float4 w2 = ((const float4*)Wl)[lane * 4 + 2];
  float4 w3 = ((const float4*)Wl)[lane * 4 + 3];
  float xs[8];
  #pragma unroll
  for (int j = 0; j < 8; ++j) xs[j] = bf2f(xv[j]);
  float s0 = xs[0]*w0.x + xs[1]*w0.z + xs[2]*w1.x + xs[3]*w1.z
           + xs[4]*w2.x + xs[5]*w2.z + xs[6]*w3.x + xs[7]*w3.z;
  float s1 = xs[0]*w0.y + xs[1]*w0.w + xs[2]*w1.y + xs[3]*w1.w
           + xs[4]*w2.y + xs[5]*w2.w + xs[6]*w3.y + xs[7]*w3.w;
  #pragma unroll
  for (int off = 32; off; off >>= 1) { s0 += __shfl_down(s0, off); s1 += __shfl_down(s1, off); }
  if (lane == 0) {
    float l0 = s0 + bl[0], l1 = s1 + bl[1];
    float mx = fmaxf(l0, l1);
    float lse = mx + logf(expf(l0 - mx) + expf(l1 - mx));
    out[(size_t)gw * 2 + 0] = l0 - lse;
    out[(size_t)gw * 2 + 1] = l1 - lse;
  }
}

extern "C" void kernel_launch(void* const* d_in, const int* in_sizes, int n_in,
                              void* d_out, int out_size, void* d_ws, size_t ws_size,
                              hipStream_t stream) {
  const float* A   = (const float*)d_in[0];
  const float* W1  = (const float*)d_in[1];
  const float* Wh0 = (const float*)d_in[2];
  const float* bh0 = (const float*)d_in[3];
  const float* Wg0 = (const float*)d_in[4];
  const float* bg0 = (const float*)d_in[5];
  const float* Wh1 = (const float*)d_in[6];
  const float* bh1 = (const float*)d_in[7];
  const float* Wg1 = (const float*)d_in[8];
  const float* bg1 = (const float*)d_in[9];
  const float* Wl  = (const float*)d_in[10];
  const float* bl  = (const float*)d_in[11];
  const int* idxx  = (const int*)d_in[12];
  const int* idxy  = (const int*)d_in[13];
  float* out = (float*)d_out;

  char* w = (char*)d_ws;
  auto carve = [&](size_t bytes) { char* p = w; w += (bytes + 255) & ~(size_t)255; return p; };
  unsigned char* W1T8  = (unsigned char*)carve((size_t)512 * KPAD2);
  unsigned short* WcT0 = (unsigned short*)carve((size_t)1024 * 512 * 2);
  unsigned short* WcT1 = (unsigned short*)carve((size_t)1024 * 512 * 2);
  unsigned short* Ppart= (unsigned short*)carve((size_t)KSPLIT * 8192 * 512 * 2);
  unsigned short* xb0  = (unsigned short*)carve((size_t)4096 * 512 * 2);
  unsigned short* xb1  = (unsigned short*)carve((size_t)4096 * 512 * 2);
  unsigned short* xb2  = (unsigned short*)carve((size_t)4096 * 512 * 2);
  int* newpos          = (int*)carve((size_t)KPAD2 * 4);
  int* rows            = (int*)carve((size_t)8256 * 4);
  int* nuniq           = (int*)carve(256);

  // weight prep + dedup (2 launches)
  prep_weights<<<dim3(6080), 256, 0, stream>>>(W1, W1T8, Wh0, Wg0, Wh1, Wg1,
      WcT0, WcT0 + (size_t)512 * 512, WcT1, WcT1 + (size_t)512 * 512);
  dedup_all<<<dim3(1), 1024, 0, stream>>>(idxx, idxy, newpos, rows, nuniq);

  // Ppart[ksp] (bf16) = (A[unique rows]*16) @ (W1*64) K-chunk (fp8, BK=128)
  gather_gemm<<<dim3(KSPLIT, 128), 512, 0, stream>>>(A, W1T8, Ppart, rows, nuniq);
  pair_combine<<<dim3(1024), 256, 0, stream>>>(Ppart, newpos, idxx, idxy, xb0);

  // fused highway layers
  hwy_gemm<<<dim3(8, 32), 256, 0, stream>>>(xb0, WcT0, bh0, bg0, xb1);
  hwy_gemm<<<dim3(8, 32), 256, 0, stream>>>(xb1, WcT1, bh1, bg1, xb2);

  logits_lsm<<<dim3(1024), 256, 0, stream>>>(xb2, Wl, bl, out);
}